// Round 4
// baseline (354.741 us; speedup 1.0000x reference)
//
#include <hip/hip_runtime.h>
#include <cstdint>
#include <cstddef>

// ---------------- problem constants ----------------
#define B_    16
#define L_    2048
#define H_    768
#define NE_   64
#define SPAN_ 4
#define NPAIR 2016              // 64*63/2
#define NROWS (B_ * NPAIR)      // 32256

typedef __bf16 bf16_t;
typedef __bf16 bf16x8 __attribute__((ext_vector_type(8)));
typedef __bf16 bf16x4 __attribute__((ext_vector_type(4)));
typedef float  floatx4 __attribute__((ext_vector_type(4)));

// ---------------- ws layout (bytes, all 256-aligned) ----------------
#define OFF_EMBH   ((size_t)3145728)
#define OFF_N      ((size_t)4718592)
#define OFF_COS    ((size_t)7864320)
#define OFF_SIM    ((size_t)8126464)
#define OFF_W1ABT  ((size_t)8255488)
#define OFF_W2T    ((size_t)10614784)
#define OFF_W3T    ((size_t)11401216)
#define OFF_C1     ((size_t)11663360)
#define OFF_H1     ((size_t)17954816)
#define OFF_H2     ((size_t)67500032)
#define OFF_H3     ((size_t)100530176)
#define OFF_FLAG   ((size_t)117045248)
#define OFF_CANON  ((size_t)117045504)
// canon bf16: [0:768) w1row0, [768:1536) b1, [1536:2048) b2,
//             [2048:2304) b3, [2304:2816) w4, [2816:2818) b4

// prep coverage: 1703936 transpose elems + 2818 canon elems = 1706754
#define PREP_TOTAL 1706754
#define PREP_GRID  ((PREP_TOTAL + 255) / 256)   // 6668 — round 3 bug: was 6667, dropped b4!

// ---------------- K0: input dtype detection ----------------
__global__ __launch_bounds__(256) void detect_kernel(
    const unsigned short* __restrict__ xu, int* __restrict__ flag) {
  __shared__ int tot[4];
  int t = threadIdx.x;
  int bad = 0;
  for (int i = t; i < 4096; i += 256) {
    int e = (xu[i] >> 7) & 0xFF;
    if (e > 133 || (e > 0 && e < 90)) bad++;
  }
  for (int off = 32; off > 0; off >>= 1) bad += __shfl_down(bad, off, 64);
  if ((t & 63) == 0) tot[t >> 6] = bad;
  __syncthreads();
  if (t == 0) flag[0] = ((tot[0] + tot[1] + tot[2] + tot[3]) > 200) ? 1 : 0;
}

__device__ inline bf16_t cvt_elem(const void* p, size_t i, int isf) {
  if (isf) return (bf16_t)(((const float*)p)[i]);
  return ((const bf16_t*)p)[i];
}

// ---------------- K0b: merged weight transposes + canonical small weights ----
__global__ __launch_bounds__(256) void prep_kernel(
    const void* __restrict__ w1, const void* __restrict__ w2,
    const void* __restrict__ w3, const void* __restrict__ b1,
    const void* __restrict__ b2, const void* __restrict__ b3,
    const void* __restrict__ w4, const void* __restrict__ b4,
    const int* __restrict__ flagp,
    bf16_t* __restrict__ w1abT, bf16_t* __restrict__ w2T,
    bf16_t* __restrict__ w3T, bf16_t* __restrict__ canon) {
  int gid = blockIdx.x * 256 + threadIdx.x;
  int isf = flagp[0];
  if (gid < 589824) {
    int idx = gid; int nn = idx / 768, kk = idx - nn * 768;
    w1abT[idx] = cvt_elem(w1, (size_t)768 + (size_t)kk * 768 + nn, isf);
  } else if (gid < 1179648) {
    int idx = gid - 589824; int nn = idx / 768, kk = idx - nn * 768;
    w1abT[589824 + idx] = cvt_elem(w1, (size_t)769 * 768 + (size_t)kk * 768 + nn, isf);
  } else if (gid < 1572864) {
    int idx = gid - 1179648; int nn = idx / 768, kk = idx - nn * 768;
    w2T[idx] = cvt_elem(w2, (size_t)kk * 512 + nn, isf);
  } else if (gid < 1703936) {
    int idx = gid - 1572864; int nn = idx / 512, kk = idx - nn * 512;
    w3T[idx] = cvt_elem(w3, (size_t)kk * 256 + nn, isf);
  } else if (gid < PREP_TOTAL) {
    int idx = gid - 1703936;
    if (idx < 768)       canon[idx] = cvt_elem(w1, idx, isf);
    else if (idx < 1536) canon[idx] = cvt_elem(b1, idx - 768, isf);
    else if (idx < 2048) canon[idx] = cvt_elem(b2, idx - 1536, isf);
    else if (idx < 2304) canon[idx] = cvt_elem(b3, idx - 2048, isf);
    else if (idx < 2816) canon[idx] = cvt_elem(w4, idx - 2304, isf);
    else                 canon[idx] = cvt_elem(b4, idx - 2816, isf);
  }
}

// ---------------- K1: span max-pool + norm ----------------
__global__ __launch_bounds__(256) void emb_kernel(
    const void* __restrict__ xv, const int* __restrict__ starts,
    const int* __restrict__ flagp,
    bf16_t* __restrict__ embh, float* __restrict__ nmat) {
  int blk = blockIdx.x;
  int b = blk >> 6, e = blk & 63;
  int st = starts[b * NE_ + e];
  size_t off = ((size_t)(b * L_ + st)) * H_;
  int t = threadIdx.x;
  int isf = flagp[0];
  float vals[3];
  float ss = 0.f;
  if (isf) {
    const float* xp = (const float*)xv + off;
#pragma unroll
    for (int c = 0; c < 3; c++) {
      int col = t + c * 256;
      float m = xp[col];
      m = fmaxf(m, xp[H_ + col]);
      m = fmaxf(m, xp[2 * H_ + col]);
      m = fmaxf(m, xp[3 * H_ + col]);
      vals[c] = m;
      ss += m * m;
    }
  } else {
    const bf16_t* xp = (const bf16_t*)xv + off;
#pragma unroll
    for (int c = 0; c < 3; c++) {
      int col = t + c * 256;
      float m = (float)xp[col];
      m = fmaxf(m, (float)xp[H_ + col]);
      m = fmaxf(m, (float)xp[2 * H_ + col]);
      m = fmaxf(m, (float)xp[3 * H_ + col]);
      vals[c] = m;
      ss += m * m;
    }
  }
  __shared__ float red[4];
  __shared__ float inv_s;
  for (int off2 = 32; off2 > 0; off2 >>= 1) ss += __shfl_down(ss, off2, 64);
  if ((t & 63) == 0) red[t >> 6] = ss;
  __syncthreads();
  if (t == 0) {
    float tot = red[0] + red[1] + red[2] + red[3];
    float norm = fmaxf(sqrtf(tot), 1e-8f);
    inv_s = 1.0f / norm;
  }
  __syncthreads();
  float inv = inv_s;
  size_t base = (size_t)blk * H_;
#pragma unroll
  for (int c = 0; c < 3; c++) {
    int col = t + c * 256;
    embh[base + col] = (bf16_t)vals[c];
    nmat[base + col] = vals[c] * inv;
  }
}

// ---------------- K2: cosine matrix (register/row-streaming) ----------------
__global__ __launch_bounds__(256) void cos_kernel(
    const float* __restrict__ nmat, float* __restrict__ cosm) {
  int b = blockIdx.x, ig = blockIdx.y;
  int t = threadIdx.x;
  int w = t >> 6, j = t & 63;
  int i0 = ig * 16 + w * 4;
  const float* nj = nmat + ((size_t)(b * NE_ + j)) * H_;
  const float* ni = nmat + ((size_t)(b * NE_ + i0)) * H_;
  float a0 = 0.f, a1 = 0.f, a2 = 0.f, a3 = 0.f;
#pragma unroll 4
  for (int k = 0; k < H_; k += 4) {
    float4 J  = *(const float4*)(nj + k);
    float4 I0 = *(const float4*)(ni + k);
    float4 I1 = *(const float4*)(ni + H_ + k);
    float4 I2 = *(const float4*)(ni + 2 * H_ + k);
    float4 I3 = *(const float4*)(ni + 3 * H_ + k);
    a0 += I0.x * J.x + I0.y * J.y + I0.z * J.z + I0.w * J.w;
    a1 += I1.x * J.x + I1.y * J.y + I1.z * J.z + I1.w * J.w;
    a2 += I2.x * J.x + I2.y * J.y + I2.z * J.z + I2.w * J.w;
    a3 += I3.x * J.x + I3.y * J.y + I3.z * J.z + I3.w * J.w;
  }
  float* outp = cosm + (size_t)b * (NE_ * NE_) + (size_t)i0 * NE_ + j;
  outp[0]       = a0;
  outp[NE_]     = a1;
  outp[2 * NE_] = a2;
  outp[3 * NE_] = a3;
}

// ---------------- K3: per-batch std (ddof=1) + sim ----------------
__global__ __launch_bounds__(256) void sim_kernel(
    const float* __restrict__ cosm, const void* __restrict__ thr_ptr,
    const int* __restrict__ flagp, float* __restrict__ sim) {
  int b = blockIdx.x, t = threadIdx.x;
  const float* cb = cosm + (size_t)b * 4096;
  __shared__ float r0[4], r1[4];
  __shared__ float mean_s, scale_s, thr_s;

  float s = 0.f;
  for (int k = t; k < 4096; k += 256) s += cb[k];
  for (int off = 32; off > 0; off >>= 1) s += __shfl_down(s, off, 64);
  if ((t & 63) == 0) r0[t >> 6] = s;
  __syncthreads();
  if (t == 0) mean_s = (r0[0] + r0[1] + r0[2] + r0[3]) * (1.0f / 4096.0f);
  __syncthreads();
  float mean = mean_s;
  float s2 = 0.f;
  for (int k = t; k < 4096; k += 256) {
    float d = cb[k] - mean;
    s2 += d * d;
  }
  for (int off = 32; off > 0; off >>= 1) s2 += __shfl_down(s2, off, 64);
  if ((t & 63) == 0) r1[t >> 6] = s2;
  __syncthreads();
  if (t == 0) {
    float var = (r1[0] + r1[1] + r1[2] + r1[3]) / 4095.0f;
    float sd = sqrtf(fmaxf(var, 0.f));
    float thv;
    if (flagp[0]) thv = *(const float*)thr_ptr;
    else          thv = (float)(*(const bf16_t*)thr_ptr);
    thr_s = thv;
    scale_s = 1.0f / (sd + 1e-5f);
  }
  __syncthreads();
  float sc = scale_s, th = thr_s;
  for (int p = t; p < NPAIR; p += 256) {
    int i = 0, rem = p;
    while (rem >= 63 - i) { rem -= 63 - i; i++; }
    int j = i + 1 + rem;
    sim[b * NPAIR + p] = (cb[i * 64 + j] - th) * sc;
  }
}

// ---------------- K5: bf16 MFMA GEMM, 128x128 tile, BK=32 (m97 structure)
template <int MODE>
__global__ __launch_bounds__(256) void gemm_kernel(
    const bf16_t* __restrict__ A, const bf16_t* __restrict__ Bt,
    void* __restrict__ Cv, const bf16_t* __restrict__ bias,
    int M, int N, int K) {
  __shared__ __align__(16) bf16_t Asm[128 * 32];
  __shared__ __align__(16) bf16_t Bsm[128 * 32];
  int bm = blockIdx.x, bn = blockIdx.y;
  int t = threadIdx.x;
  int w = t >> 6, lane = t & 63;
  int quad = lane >> 4, l15 = lane & 15;
  int wm = w >> 1, wn = w & 1;

  floatx4 acc[4][4] = {};

  const char* Abase = (const char*)(A + (size_t)bm * 128 * K);
  const char* Bbase = (const char*)(Bt + (size_t)bn * 128 * K);
  const int rowbytes = K * 2;

  for (int k0 = 0; k0 < K; k0 += 32) {
#pragma unroll
    for (int it = 0; it < 2; it++) {
      int fo = (w * 2 + it) * 1024 + lane * 16;
      int row = fo >> 6;
      int colb = fo & 63;
      const char* ga = Abase + (size_t)row * rowbytes + k0 * 2 + colb;
      const char* gb = Bbase + (size_t)row * rowbytes + k0 * 2 + colb;
      __builtin_amdgcn_global_load_lds(
          (__attribute__((address_space(1))) char*)ga,
          (__attribute__((address_space(3))) char*)((char*)Asm + (w * 2 + it) * 1024),
          16, 0, 0);
      __builtin_amdgcn_global_load_lds(
          (__attribute__((address_space(1))) char*)gb,
          (__attribute__((address_space(3))) char*)((char*)Bsm + (w * 2 + it) * 1024),
          16, 0, 0);
    }
    __syncthreads();

    bf16x8 aF[4], bF[4];
#pragma unroll
    for (int tm = 0; tm < 4; tm++) {
      int row = wm * 64 + tm * 16 + l15;
      aF[tm] = *((const bf16x8*)(Asm + row * 32 + quad * 8));
    }
#pragma unroll
    for (int tn = 0; tn < 4; tn++) {
      int row = wn * 64 + tn * 16 + l15;
      bF[tn] = *((const bf16x8*)(Bsm + row * 32 + quad * 8));
    }
#pragma unroll
    for (int tm = 0; tm < 4; tm++)
#pragma unroll
      for (int tn = 0; tn < 4; tn++)
        acc[tm][tn] = __builtin_amdgcn_mfma_f32_16x16x32_bf16(aF[tm], bF[tn], acc[tm][tn], 0, 0, 0);
    __syncthreads();
  }

  // C/D layout: row = quad*4 + reg, col = l15 (m89/m91-verified)
#pragma unroll
  for (int tm = 0; tm < 4; tm++) {
    int grow0 = bm * 128 + wm * 64 + tm * 16 + quad * 4;
#pragma unroll
    for (int tn = 0; tn < 4; tn++) {
      int gcol = bn * 128 + wn * 64 + tn * 16 + l15;
#pragma unroll
      for (int r = 0; r < 4; r++) {
        size_t o = (size_t)(grow0 + r) * N + gcol;
        float v = acc[tm][tn][r];
        if (MODE == 0) {
          ((float*)Cv)[o] = v;
        } else {
          v += (float)bias[gcol];
          v = fmaxf(v, 0.f);
          ((bf16_t*)Cv)[o] = (bf16_t)v;
        }
      }
    }
  }
}

// ---------------- K6: layer-1 assembly (float4, 192 thr) ----------------
__global__ __launch_bounds__(192) void assemble_kernel(
    const float* __restrict__ C1, const float* __restrict__ sim,
    const bf16_t* __restrict__ canon, bf16_t* __restrict__ h1) {
  int r = blockIdx.x;
  int b = r / NPAIR, p = r - b * NPAIR;
  int i = 0, rem = p;
  while (rem >= 63 - i) { rem -= 63 - i; i++; }
  int j = i + 1 + rem;
  float s = sim[b * NPAIR + p];
  const float* Ai = C1 + (size_t)(b * NE_ + i) * 1536;
  const float* Bj = C1 + (size_t)(b * NE_ + j) * 1536 + 768;
  int c = threadIdx.x * 4;
  float4 A4 = *(const float4*)(Ai + c);
  float4 B4 = *(const float4*)(Bj + c);
  bf16x4 W4 = *(const bf16x4*)(canon + c);
  bf16x4 Bi4 = *(const bf16x4*)(canon + 768 + c);
  bf16x4 o;
  o[0] = (bf16_t)fmaxf(A4.x + B4.x + s * (float)W4[0] + (float)Bi4[0], 0.f);
  o[1] = (bf16_t)fmaxf(A4.y + B4.y + s * (float)W4[1] + (float)Bi4[1], 0.f);
  o[2] = (bf16_t)fmaxf(A4.z + B4.z + s * (float)W4[2] + (float)Bi4[2], 0.f);
  o[3] = (bf16_t)fmaxf(A4.w + B4.w + s * (float)W4[3] + (float)Bi4[3], 0.f);
  *(bf16x4*)(h1 + (size_t)r * H_ + c) = o;
}

// ---------------- K7: final 256 -> 2 layer, one wave per row ----------------
__global__ __launch_bounds__(256) void final_kernel(
    const bf16_t* __restrict__ h3, const bf16_t* __restrict__ canon,
    const int* __restrict__ flagp, void* __restrict__ out) {
  int wid = threadIdx.x >> 6, lane = threadIdx.x & 63;
  int r = blockIdx.x * 4 + wid;
  const bf16_t* hp = h3 + (size_t)r * 256 + lane * 4;
  const bf16_t* wp = canon + 2304 + lane * 8;
  float a0 = 0.f, a1 = 0.f;
#pragma unroll
  for (int u = 0; u < 4; u++) {
    float hv = (float)hp[u];
    a0 += hv * (float)wp[u * 2];
    a1 += hv * (float)wp[u * 2 + 1];
  }
  for (int off = 32; off > 0; off >>= 1) {
    a0 += __shfl_down(a0, off, 64);
    a1 += __shfl_down(a1, off, 64);
  }
  if (lane == 0) {
    float o0 = a0 + (float)canon[2816];
    float o1 = a1 + (float)canon[2817];
    if (flagp[0]) {
      ((float*)out)[(size_t)r * 2]     = o0;
      ((float*)out)[(size_t)r * 2 + 1] = o1;
    } else {
      ((bf16_t*)out)[(size_t)r * 2]     = (bf16_t)o0;
      ((bf16_t*)out)[(size_t)r * 2 + 1] = (bf16_t)o1;
    }
  }
}

// ---------------- launch ----------------
extern "C" void kernel_launch(void* const* d_in, const int* in_sizes, int n_in,
                              void* d_out, int out_size, void* d_ws, size_t ws_size,
                              hipStream_t stream) {
  const void* x      = d_in[0];
  const void* thr    = d_in[1];
  const void* w1     = d_in[2];
  const void* b1     = d_in[3];
  const void* w2     = d_in[4];
  const void* b2     = d_in[5];
  const void* w3     = d_in[6];
  const void* b3     = d_in[7];
  const void* w4     = d_in[8];
  const void* b4     = d_in[9];
  const int*  starts = (const int*)d_in[10];

  char* ws = (char*)d_ws;
  bf16_t* embh  = (bf16_t*)(ws + OFF_EMBH);
  float*  nmat  = (float*)(ws + OFF_N);
  float*  cosm  = (float*)(ws + OFF_COS);
  float*  simv  = (float*)(ws + OFF_SIM);
  bf16_t* w1abT = (bf16_t*)(ws + OFF_W1ABT);
  bf16_t* w2T   = (bf16_t*)(ws + OFF_W2T);
  bf16_t* w3T   = (bf16_t*)(ws + OFF_W3T);
  float*  C1    = (float*)(ws + OFF_C1);
  bf16_t* h1    = (bf16_t*)(ws + OFF_H1);
  bf16_t* h2    = (bf16_t*)(ws + OFF_H2);
  bf16_t* h3    = (bf16_t*)(ws + OFF_H3);
  int*    flag  = (int*)(ws + OFF_FLAG);
  bf16_t* canon = (bf16_t*)(ws + OFF_CANON);

  detect_kernel<<<1, 256, 0, stream>>>((const unsigned short*)x, flag);
  prep_kernel<<<PREP_GRID, 256, 0, stream>>>(w1, w2, w3, b1, b2, b3, w4, b4, flag,
                                             w1abT, w2T, w3T, canon);
  emb_kernel<<<B_ * NE_, 256, 0, stream>>>(x, starts, flag, embh, nmat);
  {
    dim3 g(B_, 4);
    cos_kernel<<<g, 256, 0, stream>>>(nmat, cosm);
  }
  sim_kernel<<<B_, 256, 0, stream>>>(cosm, thr, flag, simv);

  // C1 = emb @ [W1a | W1b] : [1024,768] x [768,1536] -> fp32
  {
    dim3 g(1024 / 128, 1536 / 128);
    gemm_kernel<0><<<g, 256, 0, stream>>>(embh, w1abT, (void*)C1, nullptr, 1024, 1536, 768);
  }
  assemble_kernel<<<NROWS, 192, 0, stream>>>(C1, simv, canon, h1);
  // h2 = relu(h1 @ w2 + b2) : [32256,768] x [768,512]
  {
    dim3 g(NROWS / 128, 512 / 128);
    gemm_kernel<1><<<g, 256, 0, stream>>>(h1, w2T, (void*)h2, canon + 1536, NROWS, 512, 768);
  }
  // h3 = relu(h2 @ w3 + b3) : [32256,512] x [512,256]
  {
    dim3 g(NROWS / 128, 256 / 128);
    gemm_kernel<1><<<g, 256, 0, stream>>>(h2, w3T, (void*)h3, canon + 2048, NROWS, 256, 512);
  }
  final_kernel<<<NROWS / 4, 256, 0, stream>>>(h3, canon, flag, d_out);
}

// Round 5
// 352.576 us; speedup vs baseline: 1.0061x; 1.0061x over previous
//
#include <hip/hip_runtime.h>
#include <cstdint>
#include <cstddef>

// ---------------- problem constants ----------------
#define B_    16
#define L_    2048
#define H_    768
#define NE_   64
#define SPAN_ 4
#define NPAIR 2016              // 64*63/2
#define NROWS (B_ * NPAIR)      // 32256

typedef __bf16 bf16_t;
typedef __bf16 bf16x8 __attribute__((ext_vector_type(8)));
typedef __bf16 bf16x4 __attribute__((ext_vector_type(4)));
typedef float  floatx4 __attribute__((ext_vector_type(4)));

// ---------------- ws layout (bytes, all 256-aligned) ----------------
#define OFF_EMBH   ((size_t)3145728)
#define OFF_N      ((size_t)4718592)
#define OFF_COS    ((size_t)7864320)
#define OFF_SIM    ((size_t)8126464)
#define OFF_W1ABT  ((size_t)8255488)
#define OFF_W2T    ((size_t)10614784)
#define OFF_W3T    ((size_t)11401216)
#define OFF_C1     ((size_t)11663360)
#define OFF_H1     ((size_t)17954816)
#define OFF_H2     ((size_t)67500032)
#define OFF_FLAG   ((size_t)117045248)
#define OFF_CANON  ((size_t)117045504)
// canon bf16: [0:768) w1row0, [768:1536) b1, [1536:2048) b2,
//             [2048:2304) b3, [2304:2816) w4, [2816:2818) b4

// ---------------- K0: input dtype detection ----------------
__global__ __launch_bounds__(256) void detect_kernel(
    const unsigned short* __restrict__ xu, int* __restrict__ flag) {
  __shared__ int tot[4];
  int t = threadIdx.x;
  int bad = 0;
  for (int i = t; i < 4096; i += 256) {
    int e = (xu[i] >> 7) & 0xFF;
    if (e > 133 || (e > 0 && e < 90)) bad++;
  }
  for (int off = 32; off > 0; off >>= 1) bad += __shfl_down(bad, off, 64);
  if ((t & 63) == 0) tot[t >> 6] = bad;
  __syncthreads();
  if (t == 0) flag[0] = ((tot[0] + tot[1] + tot[2] + tot[3]) > 200) ? 1 : 0;
}

__device__ inline bf16_t cvt_elem(const void* p, size_t i, int isf) {
  if (isf) return (bf16_t)(((const float*)p)[i]);
  return ((const bf16_t*)p)[i];
}

// ---------------- K0b: LDS-tiled weight transposes + canon ----------------
// 32x32 tiles, coalesced read AND write (old version was 16x line-amplified).
// tile-blocks: [0,576) w1a, [576,1152) w1b, [1152,1536) w2, [1536,1664) w3,
// block 1664: canon copy.
__global__ __launch_bounds__(256) void prep_kernel(
    const void* __restrict__ w1, const void* __restrict__ w2,
    const void* __restrict__ w3, const void* __restrict__ b1,
    const void* __restrict__ b2, const void* __restrict__ b3,
    const void* __restrict__ w4, const void* __restrict__ b4,
    const int* __restrict__ flagp,
    bf16_t* __restrict__ w1abT, bf16_t* __restrict__ w2T,
    bf16_t* __restrict__ w3T, bf16_t* __restrict__ canon) {
  int blk = blockIdx.x;
  int t = threadIdx.x;
  int isf = flagp[0];
  if (blk == 1664) {
    for (int idx = t; idx < 2818; idx += 256) {
      if (idx < 768)       canon[idx] = cvt_elem(w1, idx, isf);
      else if (idx < 1536) canon[idx] = cvt_elem(b1, idx - 768, isf);
      else if (idx < 2048) canon[idx] = cvt_elem(b2, idx - 1536, isf);
      else if (idx < 2304) canon[idx] = cvt_elem(b3, idx - 2048, isf);
      else if (idx < 2816) canon[idx] = cvt_elem(w4, idx - 2304, isf);
      else                 canon[idx] = cvt_elem(b4, idx - 2816, isf);
    }
    return;
  }
  const void* src; size_t srcoff; bf16_t* dst; int K, N; int tix;
  if (blk < 576)       { src = w1; srcoff = 768;              dst = w1abT;          K = 768; N = 768; tix = blk; }
  else if (blk < 1152) { src = w1; srcoff = (size_t)769 * 768; dst = w1abT + 589824; K = 768; N = 768; tix = blk - 576; }
  else if (blk < 1536) { src = w2; srcoff = 0;                dst = w2T;            K = 768; N = 512; tix = blk - 1152; }
  else                 { src = w3; srcoff = 0;                dst = w3T;            K = 512; N = 256; tix = blk - 1536; }
  int tiles_k = K >> 5;
  int tn_t = tix / tiles_k, tk_t = tix - tn_t * tiles_k;
  __shared__ bf16_t tile[32][33];
  int ty = t >> 5, tx = t & 31;
#pragma unroll
  for (int p = 0; p < 4; p++) {
    int kk = tk_t * 32 + p * 8 + ty;
    int nn = tn_t * 32 + tx;
    tile[p * 8 + ty][tx] = cvt_elem(src, srcoff + (size_t)kk * N + nn, isf);
  }
  __syncthreads();
#pragma unroll
  for (int p = 0; p < 4; p++) {
    int nn = tn_t * 32 + p * 8 + ty;
    int kk = tk_t * 32 + tx;
    dst[(size_t)nn * K + kk] = tile[tx][p * 8 + ty];
  }
}

// ---------------- K1: span max-pool + norm ----------------
__global__ __launch_bounds__(256) void emb_kernel(
    const void* __restrict__ xv, const int* __restrict__ starts,
    const int* __restrict__ flagp,
    bf16_t* __restrict__ embh, float* __restrict__ nmat) {
  int blk = blockIdx.x;
  int b = blk >> 6, e = blk & 63;
  int st = starts[b * NE_ + e];
  size_t off = ((size_t)(b * L_ + st)) * H_;
  int t = threadIdx.x;
  int isf = flagp[0];
  float vals[3];
  float ss = 0.f;
  if (isf) {
    const float* xp = (const float*)xv + off;
#pragma unroll
    for (int c = 0; c < 3; c++) {
      int col = t + c * 256;
      float m = xp[col];
      m = fmaxf(m, xp[H_ + col]);
      m = fmaxf(m, xp[2 * H_ + col]);
      m = fmaxf(m, xp[3 * H_ + col]);
      vals[c] = m;
      ss += m * m;
    }
  } else {
    const bf16_t* xp = (const bf16_t*)xv + off;
#pragma unroll
    for (int c = 0; c < 3; c++) {
      int col = t + c * 256;
      float m = (float)xp[col];
      m = fmaxf(m, (float)xp[H_ + col]);
      m = fmaxf(m, (float)xp[2 * H_ + col]);
      m = fmaxf(m, (float)xp[3 * H_ + col]);
      vals[c] = m;
      ss += m * m;
    }
  }
  __shared__ float red[4];
  __shared__ float inv_s;
  for (int off2 = 32; off2 > 0; off2 >>= 1) ss += __shfl_down(ss, off2, 64);
  if ((t & 63) == 0) red[t >> 6] = ss;
  __syncthreads();
  if (t == 0) {
    float tot = red[0] + red[1] + red[2] + red[3];
    float norm = fmaxf(sqrtf(tot), 1e-8f);
    inv_s = 1.0f / norm;
  }
  __syncthreads();
  float inv = inv_s;
  size_t base = (size_t)blk * H_;
#pragma unroll
  for (int c = 0; c < 3; c++) {
    int col = t + c * 256;
    embh[base + col] = (bf16_t)vals[c];
    nmat[base + col] = vals[c] * inv;
  }
}

// ---------------- K2: cosine matrix (register/row-streaming) ----------------
__global__ __launch_bounds__(256) void cos_kernel(
    const float* __restrict__ nmat, float* __restrict__ cosm) {
  int b = blockIdx.x, ig = blockIdx.y;
  int t = threadIdx.x;
  int w = t >> 6, j = t & 63;
  int i0 = ig * 16 + w * 4;
  const float* nj = nmat + ((size_t)(b * NE_ + j)) * H_;
  const float* ni = nmat + ((size_t)(b * NE_ + i0)) * H_;
  float a0 = 0.f, a1 = 0.f, a2 = 0.f, a3 = 0.f;
#pragma unroll 4
  for (int k = 0; k < H_; k += 4) {
    float4 J  = *(const float4*)(nj + k);
    float4 I0 = *(const float4*)(ni + k);
    float4 I1 = *(const float4*)(ni + H_ + k);
    float4 I2 = *(const float4*)(ni + 2 * H_ + k);
    float4 I3 = *(const float4*)(ni + 3 * H_ + k);
    a0 += I0.x * J.x + I0.y * J.y + I0.z * J.z + I0.w * J.w;
    a1 += I1.x * J.x + I1.y * J.y + I1.z * J.z + I1.w * J.w;
    a2 += I2.x * J.x + I2.y * J.y + I2.z * J.z + I2.w * J.w;
    a3 += I3.x * J.x + I3.y * J.y + I3.z * J.z + I3.w * J.w;
  }
  float* outp = cosm + (size_t)b * (NE_ * NE_) + (size_t)i0 * NE_ + j;
  outp[0]       = a0;
  outp[NE_]     = a1;
  outp[2 * NE_] = a2;
  outp[3 * NE_] = a3;
}

// ---------------- K3: per-batch std (ddof=1) + sim ----------------
__global__ __launch_bounds__(256) void sim_kernel(
    const float* __restrict__ cosm, const void* __restrict__ thr_ptr,
    const int* __restrict__ flagp, float* __restrict__ sim) {
  int b = blockIdx.x, t = threadIdx.x;
  const float* cb = cosm + (size_t)b * 4096;
  __shared__ float r0[4], r1[4];
  __shared__ float mean_s, scale_s, thr_s;

  float s = 0.f;
  for (int k = t; k < 4096; k += 256) s += cb[k];
  for (int off = 32; off > 0; off >>= 1) s += __shfl_down(s, off, 64);
  if ((t & 63) == 0) r0[t >> 6] = s;
  __syncthreads();
  if (t == 0) mean_s = (r0[0] + r0[1] + r0[2] + r0[3]) * (1.0f / 4096.0f);
  __syncthreads();
  float mean = mean_s;
  float s2 = 0.f;
  for (int k = t; k < 4096; k += 256) {
    float d = cb[k] - mean;
    s2 += d * d;
  }
  for (int off = 32; off > 0; off >>= 1) s2 += __shfl_down(s2, off, 64);
  if ((t & 63) == 0) r1[t >> 6] = s2;
  __syncthreads();
  if (t == 0) {
    float var = (r1[0] + r1[1] + r1[2] + r1[3]) / 4095.0f;
    float sd = sqrtf(fmaxf(var, 0.f));
    float thv;
    if (flagp[0]) thv = *(const float*)thr_ptr;
    else          thv = (float)(*(const bf16_t*)thr_ptr);
    thr_s = thv;
    scale_s = 1.0f / (sd + 1e-5f);
  }
  __syncthreads();
  float sc = scale_s, th = thr_s;
  for (int p = t; p < NPAIR; p += 256) {
    int i = 0, rem = p;
    while (rem >= 63 - i) { rem -= 63 - i; i++; }
    int j = i + 1 + rem;
    sim[b * NPAIR + p] = (cb[i * 64 + j] - th) * sc;
  }
}

// ---------------- K5: bf16 MFMA GEMM, 128x128 tile, BK=32 (m97 structure)
template <int MODE>
__global__ __launch_bounds__(256) void gemm_kernel(
    const bf16_t* __restrict__ A, const bf16_t* __restrict__ Bt,
    void* __restrict__ Cv, const bf16_t* __restrict__ bias,
    int M, int N, int K) {
  __shared__ __align__(16) bf16_t Asm[128 * 32];
  __shared__ __align__(16) bf16_t Bsm[128 * 32];
  int bm = blockIdx.x, bn = blockIdx.y;
  int t = threadIdx.x;
  int w = t >> 6, lane = t & 63;
  int quad = lane >> 4, l15 = lane & 15;
  int wm = w >> 1, wn = w & 1;

  floatx4 acc[4][4] = {};

  const char* Abase = (const char*)(A + (size_t)bm * 128 * K);
  const char* Bbase = (const char*)(Bt + (size_t)bn * 128 * K);
  const int rowbytes = K * 2;

  for (int k0 = 0; k0 < K; k0 += 32) {
#pragma unroll
    for (int it = 0; it < 2; it++) {
      int fo = (w * 2 + it) * 1024 + lane * 16;
      int row = fo >> 6;
      int colb = fo & 63;
      const char* ga = Abase + (size_t)row * rowbytes + k0 * 2 + colb;
      const char* gb = Bbase + (size_t)row * rowbytes + k0 * 2 + colb;
      __builtin_amdgcn_global_load_lds(
          (__attribute__((address_space(1))) char*)ga,
          (__attribute__((address_space(3))) char*)((char*)Asm + (w * 2 + it) * 1024),
          16, 0, 0);
      __builtin_amdgcn_global_load_lds(
          (__attribute__((address_space(1))) char*)gb,
          (__attribute__((address_space(3))) char*)((char*)Bsm + (w * 2 + it) * 1024),
          16, 0, 0);
    }
    __syncthreads();

    bf16x8 aF[4], bF[4];
#pragma unroll
    for (int tm = 0; tm < 4; tm++) {
      int row = wm * 64 + tm * 16 + l15;
      aF[tm] = *((const bf16x8*)(Asm + row * 32 + quad * 8));
    }
#pragma unroll
    for (int tn = 0; tn < 4; tn++) {
      int row = wn * 64 + tn * 16 + l15;
      bF[tn] = *((const bf16x8*)(Bsm + row * 32 + quad * 8));
    }
#pragma unroll
    for (int tm = 0; tm < 4; tm++)
#pragma unroll
      for (int tn = 0; tn < 4; tn++)
        acc[tm][tn] = __builtin_amdgcn_mfma_f32_16x16x32_bf16(aF[tm], bF[tn], acc[tm][tn], 0, 0, 0);
    __syncthreads();
  }

  // C/D layout: row = quad*4 + reg, col = l15 (m89/m91-verified)
#pragma unroll
  for (int tm = 0; tm < 4; tm++) {
    int grow0 = bm * 128 + wm * 64 + tm * 16 + quad * 4;
#pragma unroll
    for (int tn = 0; tn < 4; tn++) {
      int gcol = bn * 128 + wn * 64 + tn * 16 + l15;
#pragma unroll
      for (int r = 0; r < 4; r++) {
        size_t o = (size_t)(grow0 + r) * N + gcol;
        float v = acc[tm][tn][r];
        if (MODE == 0) {
          ((float*)Cv)[o] = v;
        } else {
          v += (float)bias[gcol];
          v = fmaxf(v, 0.f);
          ((bf16_t*)Cv)[o] = (bf16_t)v;
        }
      }
    }
  }
}

// ---------------- K6: layer-1 assembly (float4, 192 thr) ----------------
__global__ __launch_bounds__(192) void assemble_kernel(
    const float* __restrict__ C1, const float* __restrict__ sim,
    const bf16_t* __restrict__ canon, bf16_t* __restrict__ h1) {
  int r = blockIdx.x;
  int b = r / NPAIR, p = r - b * NPAIR;
  int i = 0, rem = p;
  while (rem >= 63 - i) { rem -= 63 - i; i++; }
  int j = i + 1 + rem;
  float s = sim[b * NPAIR + p];
  const float* Ai = C1 + (size_t)(b * NE_ + i) * 1536;
  const float* Bj = C1 + (size_t)(b * NE_ + j) * 1536 + 768;
  int c = threadIdx.x * 4;
  float4 A4 = *(const float4*)(Ai + c);
  float4 B4 = *(const float4*)(Bj + c);
  bf16x4 W4 = *(const bf16x4*)(canon + c);
  bf16x4 Bi4 = *(const bf16x4*)(canon + 768 + c);
  bf16x4 o;
  o[0] = (bf16_t)fmaxf(A4.x + B4.x + s * (float)W4[0] + (float)Bi4[0], 0.f);
  o[1] = (bf16_t)fmaxf(A4.y + B4.y + s * (float)W4[1] + (float)Bi4[1], 0.f);
  o[2] = (bf16_t)fmaxf(A4.z + B4.z + s * (float)W4[2] + (float)Bi4[2], 0.f);
  o[3] = (bf16_t)fmaxf(A4.w + B4.w + s * (float)W4[3] + (float)Bi4[3], 0.f);
  *(bf16x4*)(h1 + (size_t)r * H_ + c) = o;
}

// ---------------- K8: fused layer-3 GEMM + final layer ----------------
// h3 = relu(h2 @ w3 + b3), logits = h3 @ w4 + b4, written directly.
// tile 128 rows x 256 (full N), BK=32, grid 252. Waves 2x2: each 64r x 128c,
// acc 4x8 tiles. Epilogue: bias+relu, dot w4 (fp32), shfl_xor reduce over l15,
// LDS-combine over wn, write logits.
__global__ __launch_bounds__(256) void gemm3_fused_kernel(
    const bf16_t* __restrict__ h2, const bf16_t* __restrict__ w3T,
    const bf16_t* __restrict__ canon, const int* __restrict__ flagp,
    void* __restrict__ out) {
  __shared__ __align__(16) bf16_t Asm[128 * 32];   // 8 KB
  __shared__ __align__(16) bf16_t Bsm[256 * 32];   // 16 KB
  __shared__ float part[128][2][2];                // [row][c][wn]
  __shared__ float w4s[512];
  __shared__ float b3s[256];
  int bm = blockIdx.x;
  int t = threadIdx.x;
  int w = t >> 6, lane = t & 63;
  int quad = lane >> 4, l15 = lane & 15;
  int wm = w >> 1, wn = w & 1;

  if (t < 256) {
    w4s[t]       = (float)canon[2304 + t];
    w4s[256 + t] = (float)canon[2304 + 256 + t];
    b3s[t]       = (float)canon[2048 + t];
  }

  floatx4 acc[4][8] = {};
  const char* Abase = (const char*)(h2 + (size_t)bm * 128 * 512);
  const char* Bbase = (const char*)w3T;
  // rowbytes for both A (K=512) and B (K=512) = 1024

  for (int k0 = 0; k0 < 512; k0 += 32) {
#pragma unroll
    for (int it = 0; it < 2; it++) {   // A: 8 KB
      int fo = (w * 2 + it) * 1024 + lane * 16;
      int row = fo >> 6, colb = fo & 63;
      __builtin_amdgcn_global_load_lds(
          (__attribute__((address_space(1))) char*)(Abase + (size_t)row * 1024 + k0 * 2 + colb),
          (__attribute__((address_space(3))) char*)((char*)Asm + (w * 2 + it) * 1024),
          16, 0, 0);
    }
#pragma unroll
    for (int it = 0; it < 4; it++) {   // B: 16 KB
      int fo = (w * 4 + it) * 1024 + lane * 16;
      int row = fo >> 6, colb = fo & 63;
      __builtin_amdgcn_global_load_lds(
          (__attribute__((address_space(1))) char*)(Bbase + (size_t)row * 1024 + k0 * 2 + colb),
          (__attribute__((address_space(3))) char*)((char*)Bsm + (w * 4 + it) * 1024),
          16, 0, 0);
    }
    __syncthreads();

    bf16x8 aF[4], bF[8];
#pragma unroll
    for (int tm = 0; tm < 4; tm++) {
      int row = wm * 64 + tm * 16 + l15;
      aF[tm] = *((const bf16x8*)(Asm + row * 32 + quad * 8));
    }
#pragma unroll
    for (int tn = 0; tn < 8; tn++) {
      int row = wn * 128 + tn * 16 + l15;
      bF[tn] = *((const bf16x8*)(Bsm + row * 32 + quad * 8));
    }
#pragma unroll
    for (int tm = 0; tm < 4; tm++)
#pragma unroll
      for (int tn = 0; tn < 8; tn++)
        acc[tm][tn] = __builtin_amdgcn_mfma_f32_16x16x32_bf16(aF[tm], bF[tn], acc[tm][tn], 0, 0, 0);
    __syncthreads();
  }

  // epilogue: per (tm, reg) row — relu(v+b3) dotted with w4, reduce over cols
#pragma unroll
  for (int tm = 0; tm < 4; tm++) {
#pragma unroll
    for (int reg = 0; reg < 4; reg++) {
      float p0 = 0.f, p1 = 0.f;
#pragma unroll
      for (int tn = 0; tn < 8; tn++) {
        int col = wn * 128 + tn * 16 + l15;
        float v = acc[tm][tn][reg] + b3s[col];
        v = fmaxf(v, 0.f);
        p0 += v * w4s[col * 2];
        p1 += v * w4s[col * 2 + 1];
      }
#pragma unroll
      for (int d = 1; d < 16; d <<= 1) {
        p0 += __shfl_xor(p0, d, 64);
        p1 += __shfl_xor(p1, d, 64);
      }
      if (l15 == 0) {
        int r = wm * 64 + tm * 16 + quad * 4 + reg;
        part[r][0][wn] = p0;
        part[r][1][wn] = p1;
      }
    }
  }
  __syncthreads();
  if (t < 256) {
    int r = t >> 1, c = t & 1;
    float v = part[r][c][0] + part[r][c][1] + (float)canon[2816 + c];
    size_t rg = (size_t)bm * 128 + r;
    if (flagp[0]) ((float*)out)[rg * 2 + c] = v;
    else          ((bf16_t*)out)[rg * 2 + c] = (bf16_t)v;
  }
}

// ---------------- launch ----------------
extern "C" void kernel_launch(void* const* d_in, const int* in_sizes, int n_in,
                              void* d_out, int out_size, void* d_ws, size_t ws_size,
                              hipStream_t stream) {
  const void* x      = d_in[0];
  const void* thr    = d_in[1];
  const void* w1     = d_in[2];
  const void* b1     = d_in[3];
  const void* w2     = d_in[4];
  const void* b2     = d_in[5];
  const void* w3     = d_in[6];
  const void* b3     = d_in[7];
  const void* w4     = d_in[8];
  const void* b4     = d_in[9];
  const int*  starts = (const int*)d_in[10];

  char* ws = (char*)d_ws;
  bf16_t* embh  = (bf16_t*)(ws + OFF_EMBH);
  float*  nmat  = (float*)(ws + OFF_N);
  float*  cosm  = (float*)(ws + OFF_COS);
  float*  simv  = (float*)(ws + OFF_SIM);
  bf16_t* w1abT = (bf16_t*)(ws + OFF_W1ABT);
  bf16_t* w2T   = (bf16_t*)(ws + OFF_W2T);
  bf16_t* w3T   = (bf16_t*)(ws + OFF_W3T);
  float*  C1    = (float*)(ws + OFF_C1);
  bf16_t* h1    = (bf16_t*)(ws + OFF_H1);
  bf16_t* h2    = (bf16_t*)(ws + OFF_H2);
  int*    flag  = (int*)(ws + OFF_FLAG);
  bf16_t* canon = (bf16_t*)(ws + OFF_CANON);

  detect_kernel<<<1, 256, 0, stream>>>((const unsigned short*)x, flag);
  prep_kernel<<<1665, 256, 0, stream>>>(w1, w2, w3, b1, b2, b3, w4, b4, flag,
                                        w1abT, w2T, w3T, canon);
  emb_kernel<<<B_ * NE_, 256, 0, stream>>>(x, starts, flag, embh, nmat);
  {
    dim3 g(B_, 4);
    cos_kernel<<<g, 256, 0, stream>>>(nmat, cosm);
  }
  sim_kernel<<<B_, 256, 0, stream>>>(cosm, thr, flag, simv);

  // C1 = emb @ [W1a | W1b] : [1024,768] x [768,1536] -> fp32
  {
    dim3 g(1024 / 128, 1536 / 128);
    gemm_kernel<0><<<g, 256, 0, stream>>>(embh, w1abT, (void*)C1, nullptr, 1024, 1536, 768);
  }
  assemble_kernel<<<NROWS, 192, 0, stream>>>(C1, simv, canon, h1);
  // h2 = relu(h1 @ w2 + b2) : [32256,768] x [768,512]
  {
    dim3 g(NROWS / 128, 512 / 128);
    gemm_kernel<1><<<g, 256, 0, stream>>>(h1, w2T, (void*)h2, canon + 1536, NROWS, 512, 768);
  }
  // fused: h3 = relu(h2 @ w3 + b3); logits = h3 @ w4 + b4
  gemm3_fused_kernel<<<NROWS / 128, 256, 0, stream>>>(h2, w3T, canon, flag, d_out);
}